// Round 1
// baseline (354.227 us; speedup 1.0000x reference)
//
#include <hip/hip_runtime.h>
#include <cmath>

// SSIM + L1 image similarity loss, MI355X (gfx950).
// es, ta: fp32 [16,3,512,512]. Output: out[0]=l1_loss, out[1]=ssim_loss.
//
// Design: separable 11-tap Gaussian. Per block: 64x64 output tile.
// - Stage es/ta 74x74 input tiles (halo 5, zero-padded at image border) in LDS.
// - Each of 4 waves owns 16 output rows; each lane owns one column.
// - Stream 26 input rows: horizontal 11-tap conv of {e, t, e^2, t^2, e*t}
//   (5 values in registers), then scatter-accumulate the vertical 11-tap
//   into 5x16 register accumulators (fully unrolled -> static indices).
// - Epilogue: ssim_map value per pixel + |e-t|; wave shfl_xor reduce;
//   2 atomicAdds per wave into d_ws; tiny finalize kernel writes out[2].

constexpr int TILE = 64;
constexpr int HALO = 5;
constexpr int WIN  = 11;
constexpr int LW   = TILE + 2 * HALO;  // 74
constexpr int LSTR = 76;               // padded LDS row stride
constexpr int IMG  = 512;
constexpr float C1C = 0.01f * 0.01f;   // 1e-4
constexpr float C2C = 0.03f * 0.03f;   // 9e-4

struct Wnd { float g[WIN]; };

__global__ __launch_bounds__(256) void ssim_main(
    const float* __restrict__ es, const float* __restrict__ ta,
    float* __restrict__ accbuf, Wnd w)
{
    __shared__ float sA[LW * LSTR];
    __shared__ float sB[LW * LSTR];

    const int tid = threadIdx.x;
    const int tx0 = blockIdx.x * TILE;
    const int ty0 = blockIdx.y * TILE;
    const int img = blockIdx.z;
    const float* pe = es + (size_t)img * (IMG * IMG);
    const float* pt = ta + (size_t)img * (IMG * IMG);

    // ---- stage input tiles (zero-pad outside image) ----
    for (int i = tid; i < LW * LW; i += 256) {
        int r = i / LW;
        int c = i - r * LW;
        int gy = ty0 - HALO + r;
        int gx = tx0 - HALO + c;
        float ev = 0.f, tv = 0.f;
        if (gy >= 0 && gy < IMG && gx >= 0 && gx < IMG) {
            int off = gy * IMG + gx;
            ev = pe[off];
            tv = pt[off];
        }
        sA[r * LSTR + c] = ev;
        sB[r * LSTR + c] = tv;
    }
    __syncthreads();

    const int wv = tid >> 6;   // wave id 0..3 -> 16-row segment
    const int ln = tid & 63;   // lane -> column

    float a0[16], a1[16], a2[16], a3[16], a4[16];
    #pragma unroll
    for (int o = 0; o < 16; ++o) { a0[o]=0.f; a1[o]=0.f; a2[o]=0.f; a3[o]=0.f; a4[o]=0.f; }

    const int rbase = wv * 16;

    #pragma unroll
    for (int rr = 0; rr < 26; ++rr) {
        const float* rowA = &sA[(rbase + rr) * LSTR + ln];
        const float* rowB = &sB[(rbase + rr) * LSTR + ln];
        float e[WIN], t[WIN];
        #pragma unroll
        for (int k = 0; k < WIN; ++k) { e[k] = rowA[k]; t[k] = rowB[k]; }

        float hm1 = 0.f, hm2 = 0.f, h11 = 0.f, h22 = 0.f, h12 = 0.f;
        #pragma unroll
        for (int k = 0; k < WIN; ++k) {
            float gk = w.g[k];
            float ge = gk * e[k];
            float gt = gk * t[k];
            hm1 += ge;
            hm2 += gt;
            h11 += ge * e[k];
            h22 += gt * t[k];
            h12 += ge * t[k];
        }

        // vertical scatter: input row rr contributes g[k] to output row rr-k
        #pragma unroll
        for (int k = 0; k < WIN; ++k) {
            constexpr int dummy = 0; (void)dummy;
            int o = rr - k;
            if (o >= 0 && o < 16) {
                float gk = w.g[k];
                a0[o] += gk * hm1;
                a1[o] += gk * hm2;
                a2[o] += gk * h11;
                a3[o] += gk * h22;
                a4[o] += gk * h12;
            }
        }
    }

    // ---- epilogue: ssim per pixel + L1, then reduce ----
    float ssim_s = 0.f, l1_s = 0.f;
    #pragma unroll
    for (int o = 0; o < 16; ++o) {
        float mu1 = a0[o], mu2 = a1[o];
        float m11 = mu1 * mu1, m22 = mu2 * mu2, m12 = mu1 * mu2;
        float s11 = a2[o] - m11;
        float s22 = a3[o] - m22;
        float s12 = a4[o] - m12;
        float num = (2.f * m12 + C1C) * (2.f * s12 + C2C);
        float den = (m11 + m22 + C1C) * (s11 + s22 + C2C);
        ssim_s += num * __builtin_amdgcn_rcpf(den);

        int lr = rbase + o + HALO;
        float ev = sA[lr * LSTR + ln + HALO];
        float tv = sB[lr * LSTR + ln + HALO];
        l1_s += fabsf(ev - tv);
    }

    #pragma unroll
    for (int off = 32; off >= 1; off >>= 1) {
        ssim_s += __shfl_xor(ssim_s, off, 64);
        l1_s   += __shfl_xor(l1_s, off, 64);
    }
    if (ln == 0) {
        atomicAdd(&accbuf[0], ssim_s);
        atomicAdd(&accbuf[1], l1_s);
    }
}

__global__ void ssim_finalize(const float* __restrict__ acc, float* __restrict__ out)
{
    const float N = 16.f * 3.f * 512.f * 512.f;
    out[0] = 0.15f * (acc[1] / N);
    out[1] = 0.85f * 0.5f * (1.f - acc[0] / N);
}

extern "C" void kernel_launch(void* const* d_in, const int* in_sizes, int n_in,
                              void* d_out, int out_size, void* d_ws, size_t ws_size,
                              hipStream_t stream)
{
    const float* es = (const float*)d_in[0];
    const float* ta = (const float*)d_in[1];
    float* out = (float*)d_out;
    float* acc = (float*)d_ws;

    hipMemsetAsync(acc, 0, 2 * sizeof(float), stream);

    // Gaussian window computed on host (double, then cast) — matches the
    // reference's normalized 11-tap sigma=1.5 window to fp32 accuracy.
    Wnd w;
    double gd[WIN], sum = 0.0;
    for (int i = 0; i < WIN; ++i) {
        double x = (double)(i - WIN / 2);
        gd[i] = std::exp(-(x * x) / (2.0 * 1.5 * 1.5));
        sum += gd[i];
    }
    for (int i = 0; i < WIN; ++i) w.g[i] = (float)(gd[i] / sum);

    const int nimg = in_sizes[0] / (IMG * IMG);  // 16*3 = 48
    dim3 grid(IMG / TILE, IMG / TILE, nimg);
    ssim_main<<<grid, 256, 0, stream>>>(es, ta, acc, w);
    ssim_finalize<<<1, 1, 0, stream>>>(acc, out);
}